// Round 9
// baseline (18.211 us; speedup 1.0000x reference)
//
#include <hip/hip_runtime.h>

typedef _Float16 h8 __attribute__((ext_vector_type(8)));

#define BB 32
#define NN 256
#define DD 32
#define HH 64
#define ET 64    // edge tile (64x64)
#define XST 40   // sX/sW row stride in halves (80 B): conflict-free under row permutation
#define AST 72   // sA row stride in halves (144 B)

#if defined(__has_builtin)
#  if __has_builtin(__builtin_amdgcn_fdot2)
#    define FDOT2(a, b, c) __builtin_amdgcn_fdot2((a), (b), (c), false)
#  endif
#endif
#ifndef FDOT2
#  define FDOT2(a, b, c) ((c) + (float)((a)[0]) * (float)((b)[0]) + (float)((a)[1]) * (float)((b)[1]))
#endif

__device__ __forceinline__ float sigmoidf_fast(float v) {
    return 1.0f / (1.0f + __expf(-v));
}

// One fused kernel. 64x64 tile, 256 threads, grid 512 -> 2 independent blocks/CU
// (16 waves/CU) so one block's barriers/stage latency hides under the other's compute.
// Layouts (bijective, bank-verified):
//   sX rows: i-panel r -> (r>>2)+16*(r&3); j-panel r -> 64 + (r>>2)+16*(r&3)
//   sW rows: hc -> (hc>>3)+16*(hc&7)  (hc<64 = W1a[h], hc>=64 = W1b[h] -> +8 base on read)
// Phase 2 (prep): waves 0-1 a-side, waves 2-3 c-side (wave-uniform side, zero divergence);
//   each lane: 4 rows x 8 h via v_dot2_f32_f16; c-side folds b1.
// Phase 3 (edge): 4x4 outputs/thread; per h8-chunk 8 ds_read_b128 feed 192 packed VALU.
__global__ __launch_bounds__(256) void fused_kernel(const float* __restrict__ x, const float* __restrict__ W1,
                                                    const float* __restrict__ b1, const float* __restrict__ W2,
                                                    const float* __restrict__ b2, float* __restrict__ out)
{
    __shared__ _Float16 sX[128][XST];   // rows 0-63: i-panel, 64-127: j-panel (permuted)
    __shared__ _Float16 sW[128][XST];
    __shared__ _Float16 sAi[ET][AST];
    __shared__ _Float16 sAj[ET][AST];
    __shared__ _Float16 sW2h[HH];
    __shared__ float sb1[HH];

    const int blk = blockIdx.x;
    const int jt = blk & 3;
    const int it = (blk >> 2) & 3;
    const int b  = blk >> 4;
    const int tid = threadIdx.x;
    const float* xb = x + (size_t)b * NN * DD;

    // ---- Phase 1: vectorized staging ----
    {   // W1: thread t -> hc = t>>1 (0..127), d0 = (t&1)*16; 4x float4, 2x ds_write_b128
        const int hc = tid >> 1, d0 = (tid & 1) << 4;
        const float* src = (hc < HH) ? &W1[hc * 64 + d0] : &W1[(hc - HH) * 64 + DD + d0];
        float t16[16];
        *(float4*)&t16[0]  = *(const float4*)&src[0];
        *(float4*)&t16[4]  = *(const float4*)&src[4];
        *(float4*)&t16[8]  = *(const float4*)&src[8];
        *(float4*)&t16[12] = *(const float4*)&src[12];
        const int phys = (hc >> 3) + ((hc & 7) << 4);
        h8 v0, v1;
#pragma unroll
        for (int q = 0; q < 8; ++q) { v0[q] = (_Float16)t16[q]; v1[q] = (_Float16)t16[q + 8]; }
        *(h8*)&sW[phys][d0]     = v0;
        *(h8*)&sW[phys][d0 + 8] = v1;
    }
    {   // x panels: 128 rows (64 i + 64 j) x 2 half-rows = 256 items
        const int row = tid >> 1, d0 = (tid & 1) << 4;
        const int r = row & 63;
        const int grow = ((row < 64) ? it : jt) * ET + r;
        const int phys = ((row < 64) ? 0 : 64) + (r >> 2) + ((r & 3) << 4);
        float t16[16];
        const float* src = &xb[(size_t)grow * DD + d0];
        *(float4*)&t16[0]  = *(const float4*)&src[0];
        *(float4*)&t16[4]  = *(const float4*)&src[4];
        *(float4*)&t16[8]  = *(const float4*)&src[8];
        *(float4*)&t16[12] = *(const float4*)&src[12];
        h8 v0, v1;
#pragma unroll
        for (int q = 0; q < 8; ++q) { v0[q] = (_Float16)t16[q]; v1[q] = (_Float16)t16[q + 8]; }
        *(h8*)&sX[phys][d0]     = v0;
        *(h8*)&sX[phys][d0 + 8] = v1;
    }
    if (tid < HH) sW2h[tid] = (_Float16)W2[tid];
    else if (tid < 2 * HH) sb1[tid - HH] = b1[tid - HH];
    __syncthreads();

    // ---- Phase 2: prep (side = wave-uniform; both sides structurally identical) ----
    {
        const int wid = tid >> 6, lane = tid & 63;
        const int lq = lane >> 3, lp = lane & 7;       // lp: h-group (h0 = 8*lp)
        const int side = wid >> 1;                     // 0: a-side (i), 1: c-side (j)
        const int g = (((wid & 1) << 3) | lq);         // row group 0..15; rows 4g+rr
        const int xb0 = (side << 6) + g;               // sX phys base: g + 16*rr (+64 for j)
        const int wb0 = (side << 3) + lp;              // sW phys base: (+8 for W1b)
        _Float16* dst = side ? &sAj[0][0] : &sAi[0][0];

        float pacc[4][8] = {};
#pragma unroll
        for (int ch = 0; ch < 4; ++ch) {
            h8 xv[4], wv[8];
#pragma unroll
            for (int rr = 0; rr < 4; ++rr) xv[rr] = *(const h8*)&sX[xb0 + (rr << 4)][ch << 3];
#pragma unroll
            for (int cc = 0; cc < 8; ++cc) wv[cc] = *(const h8*)&sW[wb0 + (cc << 4)][ch << 3];
#pragma unroll
            for (int rr = 0; rr < 4; ++rr)
#pragma unroll
                for (int cc = 0; cc < 8; ++cc) {
                    float a = pacc[rr][cc];
                    a = FDOT2(__builtin_shufflevector(xv[rr], xv[rr], 0, 1), __builtin_shufflevector(wv[cc], wv[cc], 0, 1), a);
                    a = FDOT2(__builtin_shufflevector(xv[rr], xv[rr], 2, 3), __builtin_shufflevector(wv[cc], wv[cc], 2, 3), a);
                    a = FDOT2(__builtin_shufflevector(xv[rr], xv[rr], 4, 5), __builtin_shufflevector(wv[cc], wv[cc], 4, 5), a);
                    a = FDOT2(__builtin_shufflevector(xv[rr], xv[rr], 6, 7), __builtin_shufflevector(wv[cc], wv[cc], 6, 7), a);
                    pacc[rr][cc] = a;
                }
        }
        float badd[8];
#pragma unroll
        for (int cc = 0; cc < 8; ++cc) badd[cc] = side ? sb1[(lp << 3) + cc] : 0.f;
#pragma unroll
        for (int rr = 0; rr < 4; ++rr) {
            h8 v;
#pragma unroll
            for (int cc = 0; cc < 8; ++cc) v[cc] = (_Float16)(pacc[rr][cc] + badd[cc]);
            *(h8*)&dst[(size_t)((g << 2) | rr) * AST + (lp << 3)] = v;
        }
    }
    __syncthreads();

    // ---- Phase 3: edge, 4x4 outputs/thread ----
    const int jl = tid & 15;    // fast dim -> coalesced stores
    const int il = tid >> 4;    // 0..15; rows il + 16r
    h8 w2v[8];
#pragma unroll
    for (int q = 0; q < 8; ++q) w2v[q] = *(const h8*)&sW2h[q << 3];

    float eacc[4][4] = {};
#pragma unroll
    for (int c8 = 0; c8 < 8; ++c8) {
        h8 av[4], cv[4];
#pragma unroll
        for (int r = 0; r < 4; ++r) av[r] = *(const h8*)&sAi[il + (r << 4)][c8 << 3];  // bcast x16, 2-way
#pragma unroll
        for (int c = 0; c < 4; ++c) cv[c] = *(const h8*)&sAj[jl + (c << 4)][c8 << 3];  // 2-way, free
#pragma unroll
        for (int r = 0; r < 4; ++r)
#pragma unroll
            for (int c = 0; c < 4; ++c) {
                h8 z  = av[r] + cv[c];                       // 4x v_pk_add_f16
                h8 rl = __builtin_elementwise_max(z, h8{});  // 4x v_pk_max_f16
                float a = eacc[r][c];
                a = FDOT2(__builtin_shufflevector(rl, rl, 0, 1), __builtin_shufflevector(w2v[c8], w2v[c8], 0, 1), a);
                a = FDOT2(__builtin_shufflevector(rl, rl, 2, 3), __builtin_shufflevector(w2v[c8], w2v[c8], 2, 3), a);
                a = FDOT2(__builtin_shufflevector(rl, rl, 4, 5), __builtin_shufflevector(w2v[c8], w2v[c8], 4, 5), a);
                a = FDOT2(__builtin_shufflevector(rl, rl, 6, 7), __builtin_shufflevector(w2v[c8], w2v[c8], 6, 7), a);
                eacc[r][c] = a;
            }
    }

    const float b2v = b2[0];
    const size_t base = (((size_t)(b * NN) + it * ET + il) << 8) + jt * ET + jl;
#pragma unroll
    for (int r = 0; r < 4; ++r)
#pragma unroll
        for (int c = 0; c < 4; ++c)
            out[base + (size_t)(r << 4) * NN + (c << 4)] = sigmoidf_fast(eacc[r][c] + b2v);
}

extern "C" void kernel_launch(void* const* d_in, const int* in_sizes, int n_in,
                              void* d_out, int out_size, void* d_ws, size_t ws_size,
                              hipStream_t stream) {
    const float* x  = (const float*)d_in[0];
    const float* W1 = (const float*)d_in[1];
    const float* b1 = (const float*)d_in[2];
    const float* W2 = (const float*)d_in[3];
    const float* b2 = (const float*)d_in[4];
    float* out = (float*)d_out;

    const int nBlocks = BB * (NN / ET) * (NN / ET);  // 32*4*4 = 512, 2 blocks/CU
    fused_kernel<<<nBlocks, 256, 0, stream>>>(x, W1, b1, W2, b2, out);
}

// Round 10
// 17.601 us; speedup vs baseline: 1.0347x; 1.0347x over previous
//
#include <hip/hip_runtime.h>

typedef _Float16 h8 __attribute__((ext_vector_type(8)));

#define BB 32
#define NN 256
#define DD 32
#define HH 64
#define XST 40   // sX/sW row stride in halves (80 B)
#define AST 72   // sAi/sAj row stride in halves (144 B)

#if defined(__has_builtin)
#  if __has_builtin(__builtin_amdgcn_fdot2)
#    define FDOT2(a, b, c) __builtin_amdgcn_fdot2((a), (b), (c), false)
#  endif
#endif
#ifndef FDOT2
#  define FDOT2(a, b, c) ((c) + (float)((a)[0]) * (float)((b)[0]) + (float)((a)[1]) * (float)((b)[1]))
#endif

__device__ __forceinline__ float sigmoidf_fast(float v) {
    return 1.0f / (1.0f + __expf(-v));
}

// One fused kernel: 128x64 tile, 512 threads, grid 256 (1 block/CU, 2 waves/SIMD).
// Layouts (bijective):
//   sX i-panel r(0..127) -> phys (r>>3)+16*(r&7); j-panel r(0..63) -> 128+(r>>3)+8*(r&7)
//   sW hc(0..127) -> phys (hc>>3)+16*(hc&7); hc<64 = W1a[h], hc>=64 = W1b[h] (+8 base on read)
//   sAi: identity rows. sAj: j(0..63) -> phys (j>>2)+16*(j&3)  [edge reads 4 consecutive j]
// Prep (3 waves, 8x8 microtile = 1.0 LDS read/result vs 1.5 before):
//   waves 0-1: a[128][64]; wave 2: c[64][64]+b1; waves 3-7 idle at barrier.
// Edge: 4 rows x 4 consecutive j per thread; per h8-chunk 8 ds_read_b128 feed 192 packed VALU;
//   stores as 4x dwordx4 (wave = 4 rows x 256B contiguous).
__global__ __launch_bounds__(512, 2) void fused_kernel(const float* __restrict__ x, const float* __restrict__ W1,
                                                       const float* __restrict__ b1, const float* __restrict__ W2,
                                                       const float* __restrict__ b2, float* __restrict__ out)
{
    __shared__ _Float16 sX[192][XST];
    __shared__ _Float16 sW[128][XST];
    __shared__ _Float16 sAi[128][AST];
    __shared__ _Float16 sAj[64][AST];
    __shared__ _Float16 sW2h[HH];
    __shared__ float sb1[HH];

    const int blk = blockIdx.x;
    const int jt = blk & 3;
    const int it = (blk >> 2) & 1;
    const int b  = blk >> 3;
    const int tid = threadIdx.x;
    const float* xb = x + (size_t)b * NN * DD;

    // ---- Phase 1: staging ----
    {   // W1: thread t -> hc = t>>2 (0..127), d0 = (t&3)*8; 2x float4 -> 1x ds_write_b128
        const int hc = tid >> 2, d0 = (tid & 3) << 3;
        const float* src = (hc < HH) ? &W1[hc * 64 + d0] : &W1[(hc - HH) * 64 + DD + d0];
        float t8[8];
        *(float4*)&t8[0] = *(const float4*)&src[0];
        *(float4*)&t8[4] = *(const float4*)&src[4];
        const int phys = (hc >> 3) + ((hc & 7) << 4);
        h8 v;
#pragma unroll
        for (int q = 0; q < 8; ++q) v[q] = (_Float16)t8[q];
        *(h8*)&sW[phys][d0] = v;
    }
    if (tid < 384) {   // x panels: 192 rows x 2 half-rows of 16
        const int row = tid >> 1, d0 = (tid & 1) << 4;
        int grow, phys;
        if (row < 128) { grow = it * 128 + row; phys = (row >> 3) + ((row & 7) << 4); }
        else { const int r = row - 128; grow = jt * 64 + r; phys = 128 + (r >> 3) + ((r & 7) << 3); }
        float t16[16];
        const float* src = &xb[(size_t)grow * DD + d0];
        *(float4*)&t16[0]  = *(const float4*)&src[0];
        *(float4*)&t16[4]  = *(const float4*)&src[4];
        *(float4*)&t16[8]  = *(const float4*)&src[8];
        *(float4*)&t16[12] = *(const float4*)&src[12];
        h8 v0, v1;
#pragma unroll
        for (int q = 0; q < 8; ++q) { v0[q] = (_Float16)t16[q]; v1[q] = (_Float16)t16[q + 8]; }
        *(h8*)&sX[phys][d0]     = v0;
        *(h8*)&sX[phys][d0 + 8] = v1;
    }
    if (tid < HH) sW2h[tid] = (_Float16)W2[tid];
    else if (tid < 2 * HH) sb1[tid - HH] = b1[tid - HH];
    __syncthreads();

    // ---- Phase 2: prep, 8x8 microtiles on waves 0-2 ----
    {
        const int wid = tid >> 6, lane = tid & 63;
        if (wid < 2) {
            // a-side: lane (rg,hg); rows 8rg+rr -> sX phys rg+16rr; W rows 8hg+cc -> phys hg+16cc
            const int rg = (wid << 3) | (lane >> 3), hg = lane & 7;
            float pacc[8][8] = {};
#pragma unroll
            for (int ch = 0; ch < 4; ++ch) {
                h8 xv[8], wv[8];
#pragma unroll
                for (int rr = 0; rr < 8; ++rr) xv[rr] = *(const h8*)&sX[rg + (rr << 4)][ch << 3];
#pragma unroll
                for (int cc = 0; cc < 8; ++cc) wv[cc] = *(const h8*)&sW[hg + (cc << 4)][ch << 3];
#pragma unroll
                for (int rr = 0; rr < 8; ++rr)
#pragma unroll
                    for (int cc = 0; cc < 8; ++cc) {
                        float a = pacc[rr][cc];
                        a = FDOT2(__builtin_shufflevector(xv[rr], xv[rr], 0, 1), __builtin_shufflevector(wv[cc], wv[cc], 0, 1), a);
                        a = FDOT2(__builtin_shufflevector(xv[rr], xv[rr], 2, 3), __builtin_shufflevector(wv[cc], wv[cc], 2, 3), a);
                        a = FDOT2(__builtin_shufflevector(xv[rr], xv[rr], 4, 5), __builtin_shufflevector(wv[cc], wv[cc], 4, 5), a);
                        a = FDOT2(__builtin_shufflevector(xv[rr], xv[rr], 6, 7), __builtin_shufflevector(wv[cc], wv[cc], 6, 7), a);
                        pacc[rr][cc] = a;
                    }
            }
#pragma unroll
            for (int rr = 0; rr < 8; ++rr) {
                h8 v;
#pragma unroll
                for (int cc = 0; cc < 8; ++cc) v[cc] = (_Float16)pacc[rr][cc];
                *(h8*)&sAi[(rg << 3) | rr][hg << 3] = v;
            }
        } else if (wid == 2) {
            // c-side: lane (lq,lp); x rows 8lq+rr -> phys 128+lq+8rr;
            // W rows hc=64+8lp+cc -> phys (8+lp)+16cc; out rows 8lq+rr -> sAj phys 2lq+(rr>>2)+16*(rr&3)
            const int lq = lane >> 3, lp = lane & 7;
            float pacc[8][8] = {};
#pragma unroll
            for (int ch = 0; ch < 4; ++ch) {
                h8 xv[8], wv[8];
#pragma unroll
                for (int rr = 0; rr < 8; ++rr) xv[rr] = *(const h8*)&sX[128 + lq + (rr << 3)][ch << 3];
#pragma unroll
                for (int cc = 0; cc < 8; ++cc) wv[cc] = *(const h8*)&sW[8 + lp + (cc << 4)][ch << 3];
#pragma unroll
                for (int rr = 0; rr < 8; ++rr)
#pragma unroll
                    for (int cc = 0; cc < 8; ++cc) {
                        float a = pacc[rr][cc];
                        a = FDOT2(__builtin_shufflevector(xv[rr], xv[rr], 0, 1), __builtin_shufflevector(wv[cc], wv[cc], 0, 1), a);
                        a = FDOT2(__builtin_shufflevector(xv[rr], xv[rr], 2, 3), __builtin_shufflevector(wv[cc], wv[cc], 2, 3), a);
                        a = FDOT2(__builtin_shufflevector(xv[rr], xv[rr], 4, 5), __builtin_shufflevector(wv[cc], wv[cc], 4, 5), a);
                        a = FDOT2(__builtin_shufflevector(xv[rr], xv[rr], 6, 7), __builtin_shufflevector(wv[cc], wv[cc], 6, 7), a);
                        pacc[rr][cc] = a;
                    }
            }
#pragma unroll
            for (int rr = 0; rr < 8; ++rr) {
                h8 v;
#pragma unroll
                for (int cc = 0; cc < 8; ++cc) v[cc] = (_Float16)(pacc[rr][cc] + sb1[(lp << 3) + cc]);
                *(h8*)&sAj[(lq << 1) + (rr >> 2) + ((rr & 3) << 4)][lp << 3] = v;
            }
        }
    }
    __syncthreads();

    // ---- Phase 3: edge. Thread: rows il+32r (r<4), cols jt*64 + 4*jl + c (c<4) ----
    const int jl = tid & 15;
    const int il = tid >> 4;   // 0..31
    h8 w2v[8];
#pragma unroll
    for (int q = 0; q < 8; ++q) w2v[q] = *(const h8*)&sW2h[q << 3];

    const float b2v = b2[0];
    float eacc[4][4];
#pragma unroll
    for (int r = 0; r < 4; ++r)
#pragma unroll
        for (int c = 0; c < 4; ++c) eacc[r][c] = b2v;

#pragma unroll
    for (int c8 = 0; c8 < 8; ++c8) {
        h8 av[4], cv[4];
#pragma unroll
        for (int r = 0; r < 4; ++r) av[r] = *(const h8*)&sAi[il + (r << 5)][c8 << 3];      // bcast x16
#pragma unroll
        for (int c = 0; c < 4; ++c) cv[c] = *(const h8*)&sAj[jl + (c << 4)][c8 << 3];      // phys(4jl+c)
#pragma unroll
        for (int r = 0; r < 4; ++r)
#pragma unroll
            for (int c = 0; c < 4; ++c) {
                h8 z  = av[r] + cv[c];                       // 4x v_pk_add_f16
                h8 rl = __builtin_elementwise_max(z, h8{});  // 4x v_pk_max_f16
                float a = eacc[r][c];
                a = FDOT2(__builtin_shufflevector(rl, rl, 0, 1), __builtin_shufflevector(w2v[c8], w2v[c8], 0, 1), a);
                a = FDOT2(__builtin_shufflevector(rl, rl, 2, 3), __builtin_shufflevector(w2v[c8], w2v[c8], 2, 3), a);
                a = FDOT2(__builtin_shufflevector(rl, rl, 4, 5), __builtin_shufflevector(w2v[c8], w2v[c8], 4, 5), a);
                a = FDOT2(__builtin_shufflevector(rl, rl, 6, 7), __builtin_shufflevector(w2v[c8], w2v[c8], 6, 7), a);
                eacc[r][c] = a;
            }
    }

    // ---- stores: 4x dwordx4, wave = 4 rows x 256B contiguous ----
#pragma unroll
    for (int r = 0; r < 4; ++r) {
        float4 o;
        o.x = sigmoidf_fast(eacc[r][0]);
        o.y = sigmoidf_fast(eacc[r][1]);
        o.z = sigmoidf_fast(eacc[r][2]);
        o.w = sigmoidf_fast(eacc[r][3]);
        *(float4*)&out[((size_t)(b * NN) + it * 128 + il + (r << 5)) * NN + jt * 64 + (jl << 2)] = o;
    }
}

extern "C" void kernel_launch(void* const* d_in, const int* in_sizes, int n_in,
                              void* d_out, int out_size, void* d_ws, size_t ws_size,
                              hipStream_t stream) {
    const float* x  = (const float*)d_in[0];
    const float* W1 = (const float*)d_in[1];
    const float* b1 = (const float*)d_in[2];
    const float* W2 = (const float*)d_in[3];
    const float* b2 = (const float*)d_in[4];
    float* out = (float*)d_out;

    const int nBlocks = BB * (NN / 128) * (NN / 64);  // 32*2*4 = 256, 1 block/CU
    fused_kernel<<<nBlocks, 512, 0, stream>>>(x, W1, b1, W2, b2, out);
}

// Round 11
// 16.977 us; speedup vs baseline: 1.0727x; 1.0368x over previous
//
#include <hip/hip_runtime.h>

typedef _Float16 h2 __attribute__((ext_vector_type(2)));
typedef _Float16 h8 __attribute__((ext_vector_type(8)));

#define BB 32
#define NN 256
#define DD 32
#define HH 64
#define ETI 128  // edge tile rows (i)
#define ETJ 64   // edge tile cols (j)
#define XST 40   // sX/sW row stride in halves (80 B): conflict-free under row permutation
#define AST 72   // sA row stride in halves (144 B)

#if defined(__has_builtin)
#  if __has_builtin(__builtin_amdgcn_fdot2)
#    define FDOT2(a, b, c) __builtin_amdgcn_fdot2((a), (b), (c), false)
#  endif
#endif
#ifndef FDOT2
#  define FDOT2(a, b, c) ((c) + (float)((a)[0]) * (float)((b)[0]) + (float)((a)[1]) * (float)((b)[1]))
#endif

__device__ __forceinline__ float sigmoidf_fast(float v) {
    return 1.0f / (1.0f + __expf(-v));
}

// Best-measured configuration (R8, 16.98 us): one fused kernel, 512 threads
// (8 waves -> 2 waves/SIMD), 128x64 output tile, 256 blocks (1/CU).
// Row permutations (bijective, verified):
//   i-panel: phys = (r>>2) + 32*(r&3)        (r in 0..127)
//   j-panel: phys = 128 + (r>>1) + 32*(r&1)  (r in 0..63)
//   W:       phys = (hc>>3) + 16*(hc&7)      (hc in 0..127; hc>=64 is W1b -> +8 base on read)
// Phase 2: waves 0-3 a-side (4 rows x 8 h per lane), waves 4-7 c-side (2 rows x 8 h + b1).
// Phase 3: 4x4 outputs/thread; per h8-chunk 8 ds_read_b128 feed 192 packed VALU.
__global__ __launch_bounds__(512) void fused_kernel(const float* __restrict__ x, const float* __restrict__ W1,
                                                    const float* __restrict__ b1, const float* __restrict__ W2,
                                                    const float* __restrict__ b2, float* __restrict__ out)
{
    __shared__ _Float16 sX[192][XST];
    __shared__ _Float16 sW[128][XST];
    __shared__ _Float16 sAi[ETI][AST];
    __shared__ _Float16 sAj[ETJ][AST];
    __shared__ _Float16 sW2h[HH];
    __shared__ float sb1[HH];

    const int blk = blockIdx.x;
    const int jt = blk & 3;
    const int it = (blk >> 2) & 1;
    const int b  = blk >> 3;
    const int tid = threadIdx.x;
    const float* xb = x + (size_t)b * NN * DD;

    // ---- Phase 1: vectorized staging ----
    {   // W1: thread t -> hc = t>>2 (0..127), d0 = (t&3)*8; 2x float4 load, 1x ds_write_b128
        const int hc = tid >> 2, d0 = (tid & 3) << 3;
        const float* src = (hc < HH) ? &W1[hc * 64 + d0] : &W1[(hc - HH) * 64 + DD + d0];
        float t8[8];
        *(float4*)&t8[0] = *(const float4*)&src[0];
        *(float4*)&t8[4] = *(const float4*)&src[4];
        const int phys = (hc >> 3) + ((hc & 7) << 4);
        h8 v;
#pragma unroll
        for (int q = 0; q < 8; ++q) v[q] = (_Float16)t8[q];
        *(h8*)&sW[phys][d0] = v;
    }
    if (tid < 384) {   // x panels: 384 half-rows of 16 d
        const int row = tid >> 1, d0 = (tid & 1) << 4;
        int grow, phys;
        if (row < 128) { grow = it * ETI + row; phys = (row >> 2) + ((row & 3) << 5); }
        else { const int r = row - 128; grow = jt * ETJ + r; phys = 128 + (r >> 1) + ((r & 1) << 5); }
        float t16[16];
        const float* src = &xb[(size_t)grow * DD + d0];
        *(float4*)&t16[0]  = *(const float4*)&src[0];
        *(float4*)&t16[4]  = *(const float4*)&src[4];
        *(float4*)&t16[8]  = *(const float4*)&src[8];
        *(float4*)&t16[12] = *(const float4*)&src[12];
        h8 v0, v1;
#pragma unroll
        for (int q = 0; q < 8; ++q) { v0[q] = (_Float16)t16[q]; v1[q] = (_Float16)t16[q + 8]; }
        *(h8*)&sX[phys][d0]     = v0;
        *(h8*)&sX[phys][d0 + 8] = v1;
    }
    if (tid < HH) sW2h[tid] = (_Float16)W2[tid];
    else if (tid < 2 * HH) sb1[tid - HH] = b1[tid - HH];
    __syncthreads();

    // ---- Phase 2: prep, side by wave (no divergence) ----
    {
        const int wid = tid >> 6, lane = tid & 63;
        const int lq = lane >> 3, lp = lane & 7;   // lp -> h-group, h0 = 8*lp
        if (wid < 4) {
            // a-side: g = 8*wid+lq (0..31); logical rows 4g+rr (rr<4); phys = g + 32*rr
            const int g = (wid << 3) | lq;
            float pacc[4][8] = {};
#pragma unroll
            for (int ch = 0; ch < 4; ++ch) {
                h8 xv[4], wv[8];
#pragma unroll
                for (int rr = 0; rr < 4; ++rr) xv[rr] = *(const h8*)&sX[g + (rr << 5)][ch << 3];
#pragma unroll
                for (int cc = 0; cc < 8; ++cc) wv[cc] = *(const h8*)&sW[lp + (cc << 4)][ch << 3];
#pragma unroll
                for (int rr = 0; rr < 4; ++rr)
#pragma unroll
                    for (int cc = 0; cc < 8; ++cc) {
                        float a = pacc[rr][cc];
                        a = FDOT2(__builtin_shufflevector(xv[rr], xv[rr], 0, 1), __builtin_shufflevector(wv[cc], wv[cc], 0, 1), a);
                        a = FDOT2(__builtin_shufflevector(xv[rr], xv[rr], 2, 3), __builtin_shufflevector(wv[cc], wv[cc], 2, 3), a);
                        a = FDOT2(__builtin_shufflevector(xv[rr], xv[rr], 4, 5), __builtin_shufflevector(wv[cc], wv[cc], 4, 5), a);
                        a = FDOT2(__builtin_shufflevector(xv[rr], xv[rr], 6, 7), __builtin_shufflevector(wv[cc], wv[cc], 6, 7), a);
                        pacc[rr][cc] = a;
                    }
            }
#pragma unroll
            for (int rr = 0; rr < 4; ++rr) {
                h8 v;
#pragma unroll
                for (int cc = 0; cc < 8; ++cc) v[cc] = (_Float16)pacc[rr][cc];
                *(h8*)&sAi[(g << 2) | rr][lp << 3] = v;
            }
        } else {
            // c-side: g = 8*(wid-4)+lq (0..31); logical rows 2g+rr (rr<2); phys = 128 + g + 32*rr
            // W rows hc = 64+8*lp+cc -> phys = (8+lp)+16*cc  (keep the +8!)
            const int g = ((wid - 4) << 3) | lq;
            float pacc[2][8] = {};
#pragma unroll
            for (int ch = 0; ch < 4; ++ch) {
                h8 xv[2], wv[8];
#pragma unroll
                for (int rr = 0; rr < 2; ++rr) xv[rr] = *(const h8*)&sX[128 + g + (rr << 5)][ch << 3];
#pragma unroll
                for (int cc = 0; cc < 8; ++cc) wv[cc] = *(const h8*)&sW[8 + lp + (cc << 4)][ch << 3];
#pragma unroll
                for (int rr = 0; rr < 2; ++rr)
#pragma unroll
                    for (int cc = 0; cc < 8; ++cc) {
                        float a = pacc[rr][cc];
                        a = FDOT2(__builtin_shufflevector(xv[rr], xv[rr], 0, 1), __builtin_shufflevector(wv[cc], wv[cc], 0, 1), a);
                        a = FDOT2(__builtin_shufflevector(xv[rr], xv[rr], 2, 3), __builtin_shufflevector(wv[cc], wv[cc], 2, 3), a);
                        a = FDOT2(__builtin_shufflevector(xv[rr], xv[rr], 4, 5), __builtin_shufflevector(wv[cc], wv[cc], 4, 5), a);
                        a = FDOT2(__builtin_shufflevector(xv[rr], xv[rr], 6, 7), __builtin_shufflevector(wv[cc], wv[cc], 6, 7), a);
                        pacc[rr][cc] = a;
                    }
            }
#pragma unroll
            for (int rr = 0; rr < 2; ++rr) {
                h8 v;
#pragma unroll
                for (int cc = 0; cc < 8; ++cc) v[cc] = (_Float16)(pacc[rr][cc] + sb1[(lp << 3) + cc]);
                *(h8*)&sAj[(g << 1) | rr][lp << 3] = v;
            }
        }
    }
    __syncthreads();

    // ---- Phase 3: edge, 4x4 outputs/thread ----
    const int jl = tid & 15;    // fast dim -> coalesced stores
    const int il = tid >> 4;    // 0..31; rows il + 32*r
    h8 w2v[8];
#pragma unroll
    for (int q = 0; q < 8; ++q) w2v[q] = *(const h8*)&sW2h[q << 3];

    float eacc[4][4] = {};
#pragma unroll
    for (int c8 = 0; c8 < 8; ++c8) {
        h8 av[4], cv[4];
#pragma unroll
        for (int r = 0; r < 4; ++r) av[r] = *(const h8*)&sAi[il + (r << 5)][c8 << 3];  // 4 quads, bcast x16
#pragma unroll
        for (int c = 0; c < 4; ++c) cv[c] = *(const h8*)&sAj[jl + (c << 4)][c8 << 3];  // 2-way, free
#pragma unroll
        for (int r = 0; r < 4; ++r)
#pragma unroll
            for (int c = 0; c < 4; ++c) {
                h8 z  = av[r] + cv[c];                       // 4x v_pk_add_f16
                h8 rl = __builtin_elementwise_max(z, h8{});  // 4x v_pk_max_f16
                float a = eacc[r][c];
                a = FDOT2(__builtin_shufflevector(rl, rl, 0, 1), __builtin_shufflevector(w2v[c8], w2v[c8], 0, 1), a);
                a = FDOT2(__builtin_shufflevector(rl, rl, 2, 3), __builtin_shufflevector(w2v[c8], w2v[c8], 2, 3), a);
                a = FDOT2(__builtin_shufflevector(rl, rl, 4, 5), __builtin_shufflevector(w2v[c8], w2v[c8], 4, 5), a);
                a = FDOT2(__builtin_shufflevector(rl, rl, 6, 7), __builtin_shufflevector(w2v[c8], w2v[c8], 6, 7), a);
                eacc[r][c] = a;
            }
    }

    const float b2v = b2[0];
    const size_t base = (((size_t)(b * NN) + it * ETI + il) << 8) + jt * ETJ + jl;
#pragma unroll
    for (int r = 0; r < 4; ++r)
#pragma unroll
        for (int c = 0; c < 4; ++c)
            out[base + (size_t)(r << 5) * NN + (c << 4)] = sigmoidf_fast(eacc[r][c] + b2v);
}

extern "C" void kernel_launch(void* const* d_in, const int* in_sizes, int n_in,
                              void* d_out, int out_size, void* d_ws, size_t ws_size,
                              hipStream_t stream) {
    const float* x  = (const float*)d_in[0];
    const float* W1 = (const float*)d_in[1];
    const float* b1 = (const float*)d_in[2];
    const float* W2 = (const float*)d_in[3];
    const float* b2 = (const float*)d_in[4];
    float* out = (float*)d_out;

    const int nBlocks = BB * (NN / ETI) * (NN / ETJ);  // 32*2*4 = 256, 1/CU
    fused_kernel<<<nBlocks, 512, 0, stream>>>(x, W1, b1, W2, b2, out);
}